// Round 1
// baseline (3439.708 us; speedup 1.0000x reference)
//
#include <hip/hip_runtime.h>
#include <math.h>

#define T_   1024
#define D_   2048
#define HD_  128
#define NH_  16
#define KVH_ 4
#define E_   8
#define I_   1408
#define SI_  5632

#define BM 128
#define BN 64
#define BKT 16

// ---------------- RMSNorm ----------------
__global__ __launch_bounds__(256) void rmsnorm_k(const float* __restrict__ x,
                                                 const float* __restrict__ w,
                                                 float* __restrict__ y) {
    int t = blockIdx.x;
    const float4* row = (const float4*)(x + (size_t)t * D_);
    float4 v0 = row[threadIdx.x];
    float4 v1 = row[threadIdx.x + 256];
    float ss = v0.x*v0.x + v0.y*v0.y + v0.z*v0.z + v0.w*v0.w
             + v1.x*v1.x + v1.y*v1.y + v1.z*v1.z + v1.w*v1.w;
    __shared__ float red[4];
    int lane = threadIdx.x & 63, wid = threadIdx.x >> 6;
    #pragma unroll
    for (int o = 32; o > 0; o >>= 1) ss += __shfl_down(ss, o, 64);
    if (lane == 0) red[wid] = ss;
    __syncthreads();
    float s = red[0] + red[1] + red[2] + red[3];
    float inv = rsqrtf(s * (1.0f / D_) + 1e-6f);
    const float4* wv = (const float4*)w;
    float4* outp = (float4*)(y + (size_t)t * D_);
    float4 w0 = wv[threadIdx.x], w1 = wv[threadIdx.x + 256];
    float4 o0, o1;
    o0.x = v0.x * inv * w0.x; o0.y = v0.y * inv * w0.y;
    o0.z = v0.z * inv * w0.z; o0.w = v0.w * inv * w0.w;
    o1.x = v1.x * inv * w1.x; o1.y = v1.y * inv * w1.y;
    o1.z = v1.z * inv * w1.z; o1.w = v1.w * inv * w1.w;
    outp[threadIdx.x] = o0;
    outp[threadIdx.x + 256] = o1;
}

// ---------------- generic C = A @ B^T (+bias)(+residual)(*scale), batched ----------------
__global__ __launch_bounds__(256) void gemm_bt(
    const float* __restrict__ A, int lda, long sAz,
    const float* __restrict__ B, int ldb, long sBz, int bdiv,
    float* __restrict__ C, int ldc, long sCz,
    const float* __restrict__ bias,
    const float* __restrict__ residual,
    float scale, int K, int causal)
{
    int m0 = blockIdx.y * BM, n0 = blockIdx.x * BN, z = blockIdx.z;
    if (causal && n0 >= m0 + BM) return;
    A += sAz * (long)z;
    B += sBz * (long)(z / bdiv);
    C += sCz * (long)z;
    __shared__ float As[BKT][BM + 4];
    __shared__ float Bs[BKT][BN + 4];
    int tid = threadIdx.x, tx = tid & 15, ty = tid >> 4;
    float acc[8][4] = {};
    for (int k0 = 0; k0 < K; k0 += BKT) {
        #pragma unroll
        for (int l = 0; l < 2; l++) {
            int f = tid + l * 256, row = f >> 2, kq = (f & 3) << 2;
            float4 v = *(const float4*)(A + (size_t)(m0 + row) * lda + k0 + kq);
            As[kq][row] = v.x; As[kq+1][row] = v.y; As[kq+2][row] = v.z; As[kq+3][row] = v.w;
        }
        {
            int f = tid, row = f >> 2, kq = (f & 3) << 2;
            float4 v = *(const float4*)(B + (size_t)(n0 + row) * ldb + k0 + kq);
            Bs[kq][row] = v.x; Bs[kq+1][row] = v.y; Bs[kq+2][row] = v.z; Bs[kq+3][row] = v.w;
        }
        __syncthreads();
        #pragma unroll
        for (int kk = 0; kk < BKT; kk++) {
            float4 a0 = *(const float4*)&As[kk][ty * 8];
            float4 a1 = *(const float4*)&As[kk][ty * 8 + 4];
            float4 b  = *(const float4*)&Bs[kk][tx * 4];
            float av[8] = {a0.x,a0.y,a0.z,a0.w,a1.x,a1.y,a1.z,a1.w};
            float bv[4] = {b.x,b.y,b.z,b.w};
            #pragma unroll
            for (int i = 0; i < 8; i++)
                #pragma unroll
                for (int j = 0; j < 4; j++)
                    acc[i][j] = fmaf(av[i], bv[j], acc[i][j]);
        }
        __syncthreads();
    }
    float bb[4] = {0.f, 0.f, 0.f, 0.f};
    if (bias) {
        float4 b = *(const float4*)(bias + n0 + tx * 4);
        bb[0]=b.x; bb[1]=b.y; bb[2]=b.z; bb[3]=b.w;
    }
    #pragma unroll
    for (int i = 0; i < 8; i++) {
        int row = m0 + ty * 8 + i;
        float4 o;
        o.x = acc[i][0] * scale + bb[0];
        o.y = acc[i][1] * scale + bb[1];
        o.z = acc[i][2] * scale + bb[2];
        o.w = acc[i][3] * scale + bb[3];
        if (residual) {
            float4 r = *(const float4*)(residual + (size_t)row * ldc + n0 + tx * 4);
            o.x += r.x; o.y += r.y; o.z += r.z; o.w += r.w;
        }
        *(float4*)(C + (size_t)row * ldc + n0 + tx * 4) = o;
    }
}

// ---------------- PV: C = P @ V (B row-major [K,N]), causal K-limit ----------------
__global__ __launch_bounds__(256) void gemm_bn_pv(
    const float* __restrict__ A, int lda, long sAz,
    const float* __restrict__ B, int ldb, long sBz, int bdiv,
    float* __restrict__ C, int ldc, long sCz)
{
    int m0 = blockIdx.y * BM, n0 = blockIdx.x * BN, z = blockIdx.z;
    A += sAz * (long)z;
    B += sBz * (long)(z / bdiv);
    C += sCz * (long)z;
    int Keff = m0 + BM;  // causal: P rows in this tile are zero beyond m0+127
    __shared__ float As[BKT][BM + 4];
    __shared__ float Bs[BKT][BN + 4];
    int tid = threadIdx.x, tx = tid & 15, ty = tid >> 4;
    float acc[8][4] = {};
    for (int k0 = 0; k0 < Keff; k0 += BKT) {
        #pragma unroll
        for (int l = 0; l < 2; l++) {
            int f = tid + l * 256, row = f >> 2, kq = (f & 3) << 2;
            float4 v = *(const float4*)(A + (size_t)(m0 + row) * lda + k0 + kq);
            As[kq][row] = v.x; As[kq+1][row] = v.y; As[kq+2][row] = v.z; As[kq+3][row] = v.w;
        }
        {
            int f = tid, kr = f >> 4, nq = (f & 15) << 2;
            float4 v = *(const float4*)(B + (size_t)(k0 + kr) * ldb + n0 + nq);
            *(float4*)&Bs[kr][nq] = v;
        }
        __syncthreads();
        #pragma unroll
        for (int kk = 0; kk < BKT; kk++) {
            float4 a0 = *(const float4*)&As[kk][ty * 8];
            float4 a1 = *(const float4*)&As[kk][ty * 8 + 4];
            float4 b  = *(const float4*)&Bs[kk][tx * 4];
            float av[8] = {a0.x,a0.y,a0.z,a0.w,a1.x,a1.y,a1.z,a1.w};
            float bv[4] = {b.x,b.y,b.z,b.w};
            #pragma unroll
            for (int i = 0; i < 8; i++)
                #pragma unroll
                for (int j = 0; j < 4; j++)
                    acc[i][j] = fmaf(av[i], bv[j], acc[i][j]);
        }
        __syncthreads();
    }
    #pragma unroll
    for (int i = 0; i < 8; i++) {
        int row = m0 + ty * 8 + i;
        float4 o;
        o.x = acc[i][0]; o.y = acc[i][1]; o.z = acc[i][2]; o.w = acc[i][3];
        *(float4*)(C + (size_t)row * ldc + n0 + tx * 4) = o;
    }
}

// ---------------- RoPE in-place on q (16 heads) and k (4 heads) ----------------
__global__ __launch_bounds__(256) void rope_k(float* __restrict__ q,
                                              float* __restrict__ k,
                                              const int* __restrict__ pos_ids) {
    int t = blockIdx.x;
    float pos = (float)pos_ids[t];
    for (int p = threadIdx.x; p < 20 * 64; p += 256) {
        int hh = p >> 6, d = p & 63;
        float fr = powf(1.0e6f, -(float)(2 * d) * (1.0f / 128.0f));
        float ang = pos * fr;
        float s, c;
        sincosf(ang, &s, &c);
        float* base = (hh < 16) ? (q + (size_t)t * D_ + hh * HD_)
                                : (k + (size_t)t * (KVH_ * HD_) + (hh - 16) * HD_);
        float x1 = base[d], x2 = base[d + 64];
        base[d]      = x1 * c - x2 * s;
        base[d + 64] = x2 * c + x1 * s;
    }
}

// ---------------- causal softmax, in-place; zero-fills k>q ----------------
__global__ __launch_bounds__(256) void softmax_k(float* __restrict__ scores) {
    int qi = blockIdx.x, h = blockIdx.y;
    float* row = scores + ((size_t)h * T_ + qi) * T_;
    int len = qi + 1;
    __shared__ float red[4];
    int lane = threadIdx.x & 63, wid = threadIdx.x >> 6;
    float m = -3.0e38f;
    for (int i = threadIdx.x; i < len; i += 256) m = fmaxf(m, row[i]);
    #pragma unroll
    for (int o = 32; o > 0; o >>= 1) m = fmaxf(m, __shfl_down(m, o, 64));
    if (lane == 0) red[wid] = m;
    __syncthreads();
    m = fmaxf(fmaxf(red[0], red[1]), fmaxf(red[2], red[3]));
    __syncthreads();
    float s = 0.f;
    for (int i = threadIdx.x; i < len; i += 256) {
        float e = expf(row[i] - m);
        row[i] = e;
        s += e;
    }
    #pragma unroll
    for (int o = 32; o > 0; o >>= 1) s += __shfl_down(s, o, 64);
    if (lane == 0) red[wid] = s;
    __syncthreads();
    s = red[0] + red[1] + red[2] + red[3];
    float inv = 1.0f / s;
    for (int i = threadIdx.x; i < len; i += 256) row[i] *= inv;
    for (int i = len + threadIdx.x; i < T_; i += 256) row[i] = 0.f;
}

// ---------------- router: logits, softmax, top-2, shared-expert sigmoid gate ----------------
__global__ __launch_bounds__(256) void router_k(
    const float* __restrict__ x2, const float* __restrict__ rw,
    const float* __restrict__ seg,
    int* __restrict__ topk_i, float* __restrict__ topk_w,
    int* __restrict__ counts, float* __restrict__ sgate)
{
    int t = blockIdx.x;
    const float4* xr = (const float4*)(x2 + (size_t)t * D_);
    float part[9];
    #pragma unroll
    for (int e = 0; e < 9; e++) part[e] = 0.f;
    for (int i = threadIdx.x; i < D_ / 4; i += 256) {
        float4 xv = xr[i];
        #pragma unroll
        for (int e = 0; e < 8; e++) {
            float4 wv = ((const float4*)(rw + (size_t)e * D_))[i];
            part[e] += xv.x*wv.x + xv.y*wv.y + xv.z*wv.z + xv.w*wv.w;
        }
        float4 gv = ((const float4*)seg)[i];
        part[8] += xv.x*gv.x + xv.y*gv.y + xv.z*gv.z + xv.w*gv.w;
    }
    __shared__ float red[9][4];
    int lane = threadIdx.x & 63, wid = threadIdx.x >> 6;
    #pragma unroll
    for (int e = 0; e < 9; e++) {
        float v = part[e];
        #pragma unroll
        for (int o = 32; o > 0; o >>= 1) v += __shfl_down(v, o, 64);
        if (lane == 0) red[e][wid] = v;
    }
    __syncthreads();
    if (threadIdx.x == 0) {
        float lg[9];
        #pragma unroll
        for (int e = 0; e < 9; e++) lg[e] = red[e][0] + red[e][1] + red[e][2] + red[e][3];
        float mx = lg[0];
        for (int e = 1; e < 8; e++) mx = fmaxf(mx, lg[e]);
        float p[8], s = 0.f;
        for (int e = 0; e < 8; e++) { p[e] = expf(lg[e] - mx); s += p[e]; }
        float invs = 1.0f / s;
        for (int e = 0; e < 8; e++) p[e] *= invs;
        int i0 = 0;
        for (int e = 1; e < 8; e++) if (p[e] > p[i0]) i0 = e;
        int i1 = (i0 == 0) ? 1 : 0;
        for (int e = 0; e < 8; e++) if (e != i0 && p[e] > p[i1]) i1 = e;
        topk_i[2*t] = i0; topk_i[2*t+1] = i1;
        topk_w[2*t] = p[i0]; topk_w[2*t+1] = p[i1];
        atomicAdd(&counts[i0], 1);
        atomicAdd(&counts[i1], 1);
        sgate[t] = 1.0f / (1.0f + expf(-lg[8]));
    }
}

__global__ void offsets_k(const int* __restrict__ counts, int* __restrict__ offs) {
    if (threadIdx.x == 0 && blockIdx.x == 0) {
        int o = 0;
        for (int e = 0; e < E_; e++) {
            offs[e] = o;
            o += (counts[e] + BM - 1) & ~(BM - 1);
        }
    }
}

__global__ __launch_bounds__(256) void scatter_k(
    const int* __restrict__ topk_i, const float* __restrict__ topk_w,
    const int* __restrict__ offs, int* __restrict__ cursor,
    int* __restrict__ pair_token, float* __restrict__ pair_w,
    int* __restrict__ tok_slot)
{
    int t = blockIdx.x * 256 + threadIdx.x;
    if (t >= T_) return;
    #pragma unroll
    for (int j = 0; j < 2; j++) {
        int e = topk_i[2*t+j];
        int pos = atomicAdd(&cursor[e], 1);
        int slot = offs[e] + pos;
        pair_token[slot] = t;
        pair_w[slot] = topk_w[2*t+j];
        tok_slot[2*t+j] = slot;
    }
}

// ---------------- MoE phase1: gathered rows, dual-B (gate/up), fused SiLU*up ----------------
__global__ __launch_bounds__(256) void moe_phase1(
    const float* __restrict__ X,
    const float* __restrict__ Wg, const float* __restrict__ Wu,
    const int* __restrict__ pair_token,
    const int* __restrict__ counts, const int* __restrict__ offs,
    float* __restrict__ act)
{
    int e = blockIdx.z;
    int cnt = counts[e];
    int padded = (cnt + BM - 1) & ~(BM - 1);
    int m0 = blockIdx.y * BM;
    if (m0 >= padded) return;
    int n0 = blockIdx.x * BN;
    int base = offs[e];
    const float* Bg = Wg + (size_t)e * I_ * D_;
    const float* Bu = Wu + (size_t)e * I_ * D_;
    __shared__ float As[BKT][BM + 4];
    __shared__ float Bgs[BKT][BN + 4];
    __shared__ float Bus[BKT][BN + 4];
    __shared__ int rowtok[BM];
    int tid = threadIdx.x, tx = tid & 15, ty = tid >> 4;
    if (tid < BM) rowtok[tid] = pair_token[base + m0 + tid];
    __syncthreads();
    float accg[8][4] = {}, accu[8][4] = {};
    for (int k0 = 0; k0 < D_; k0 += BKT) {
        #pragma unroll
        for (int l = 0; l < 2; l++) {
            int f = tid + l * 256, row = f >> 2, kq = (f & 3) << 2;
            int tk = rowtok[row];
            float4 v = make_float4(0.f, 0.f, 0.f, 0.f);
            if (tk >= 0) v = *(const float4*)(X + (size_t)tk * D_ + k0 + kq);
            As[kq][row] = v.x; As[kq+1][row] = v.y; As[kq+2][row] = v.z; As[kq+3][row] = v.w;
        }
        {
            int f = tid, row = f >> 2, kq = (f & 3) << 2;
            float4 vg = *(const float4*)(Bg + (size_t)(n0 + row) * D_ + k0 + kq);
            float4 vu = *(const float4*)(Bu + (size_t)(n0 + row) * D_ + k0 + kq);
            Bgs[kq][row]=vg.x; Bgs[kq+1][row]=vg.y; Bgs[kq+2][row]=vg.z; Bgs[kq+3][row]=vg.w;
            Bus[kq][row]=vu.x; Bus[kq+1][row]=vu.y; Bus[kq+2][row]=vu.z; Bus[kq+3][row]=vu.w;
        }
        __syncthreads();
        #pragma unroll
        for (int kk = 0; kk < BKT; kk++) {
            float4 a0 = *(const float4*)&As[kk][ty * 8];
            float4 a1 = *(const float4*)&As[kk][ty * 8 + 4];
            float4 bg = *(const float4*)&Bgs[kk][tx * 4];
            float4 bu = *(const float4*)&Bus[kk][tx * 4];
            float av[8] = {a0.x,a0.y,a0.z,a0.w,a1.x,a1.y,a1.z,a1.w};
            float bgv[4] = {bg.x,bg.y,bg.z,bg.w};
            float buv[4] = {bu.x,bu.y,bu.z,bu.w};
            #pragma unroll
            for (int i = 0; i < 8; i++)
                #pragma unroll
                for (int j = 0; j < 4; j++) {
                    accg[i][j] = fmaf(av[i], bgv[j], accg[i][j]);
                    accu[i][j] = fmaf(av[i], buv[j], accu[i][j]);
                }
        }
        __syncthreads();
    }
    #pragma unroll
    for (int i = 0; i < 8; i++) {
        int slot = base + m0 + ty * 8 + i;
        float4 o;
        float g, u;
        g = accg[i][0]; u = accu[i][0]; o.x = g / (1.f + expf(-g)) * u;
        g = accg[i][1]; u = accu[i][1]; o.y = g / (1.f + expf(-g)) * u;
        g = accg[i][2]; u = accu[i][2]; o.z = g / (1.f + expf(-g)) * u;
        g = accg[i][3]; u = accu[i][3]; o.w = g / (1.f + expf(-g)) * u;
        *(float4*)(act + (size_t)slot * I_ + n0 + tx * 4) = o;
    }
}

// ---------------- MoE phase2: down-proj, weight folded in ----------------
__global__ __launch_bounds__(256) void moe_phase2(
    const float* __restrict__ act, const float* __restrict__ Wd,
    const int* __restrict__ pair_token, const float* __restrict__ pair_w,
    const int* __restrict__ counts, const int* __restrict__ offs,
    float* __restrict__ out_pair)
{
    int e = blockIdx.z;
    int cnt = counts[e];
    int padded = (cnt + BM - 1) & ~(BM - 1);
    int m0 = blockIdx.y * BM;
    if (m0 >= padded) return;
    int n0 = blockIdx.x * BN;
    int base = offs[e];
    const float* A = act + (size_t)base * I_;
    const float* B = Wd + (size_t)e * D_ * I_;
    __shared__ float As[BKT][BM + 4];
    __shared__ float Bs[BKT][BN + 4];
    int tid = threadIdx.x, tx = tid & 15, ty = tid >> 4;
    float acc[8][4] = {};
    for (int k0 = 0; k0 < I_; k0 += BKT) {
        #pragma unroll
        for (int l = 0; l < 2; l++) {
            int f = tid + l * 256, row = f >> 2, kq = (f & 3) << 2;
            float4 v = *(const float4*)(A + (size_t)(m0 + row) * I_ + k0 + kq);
            As[kq][row] = v.x; As[kq+1][row] = v.y; As[kq+2][row] = v.z; As[kq+3][row] = v.w;
        }
        {
            int f = tid, row = f >> 2, kq = (f & 3) << 2;
            float4 v = *(const float4*)(B + (size_t)(n0 + row) * I_ + k0 + kq);
            Bs[kq][row] = v.x; Bs[kq+1][row] = v.y; Bs[kq+2][row] = v.z; Bs[kq+3][row] = v.w;
        }
        __syncthreads();
        #pragma unroll
        for (int kk = 0; kk < BKT; kk++) {
            float4 a0 = *(const float4*)&As[kk][ty * 8];
            float4 a1 = *(const float4*)&As[kk][ty * 8 + 4];
            float4 b  = *(const float4*)&Bs[kk][tx * 4];
            float av[8] = {a0.x,a0.y,a0.z,a0.w,a1.x,a1.y,a1.z,a1.w};
            float bv[4] = {b.x,b.y,b.z,b.w};
            #pragma unroll
            for (int i = 0; i < 8; i++)
                #pragma unroll
                for (int j = 0; j < 4; j++)
                    acc[i][j] = fmaf(av[i], bv[j], acc[i][j]);
        }
        __syncthreads();
    }
    #pragma unroll
    for (int i = 0; i < 8; i++) {
        int slot = base + m0 + ty * 8 + i;
        int tk = pair_token[slot];
        if (tk < 0) continue;
        float w = pair_w[slot];
        float4 o;
        o.x = acc[i][0] * w; o.y = acc[i][1] * w;
        o.z = acc[i][2] * w; o.w = acc[i][3] * w;
        *(float4*)(out_pair + (size_t)slot * D_ + n0 + tx * 4) = o;
    }
}

// ---------------- shared expert SiLU*up ----------------
__global__ __launch_bounds__(256) void silumul_k(float* __restrict__ g,
                                                 const float* __restrict__ u) {
    size_t i = (size_t)blockIdx.x * 256 + threadIdx.x;
    float4 gv = ((const float4*)g)[i];
    float4 uv = ((const float4*)u)[i];
    float4 o;
    o.x = gv.x / (1.f + expf(-gv.x)) * uv.x;
    o.y = gv.y / (1.f + expf(-gv.y)) * uv.y;
    o.z = gv.z / (1.f + expf(-gv.z)) * uv.z;
    o.w = gv.w / (1.f + expf(-gv.w)) * uv.w;
    ((float4*)g)[i] = o;
}

// ---------------- shared-down GEMM + final combine ----------------
__global__ __launch_bounds__(256) void shared_down_final(
    const float* __restrict__ A,        // sh_act [T, SI]
    const float* __restrict__ B,        // shared_down [D, SI]
    const float* __restrict__ h,        // residual2 [T, D]
    const float* __restrict__ out_pair, // [slots, D], weights folded
    const int* __restrict__ tok_slot,   // [T,2]
    const float* __restrict__ sgate,    // [T]
    float* __restrict__ out)
{
    int m0 = blockIdx.y * BM, n0 = blockIdx.x * BN;
    __shared__ float As[BKT][BM + 4];
    __shared__ float Bs[BKT][BN + 4];
    int tid = threadIdx.x, tx = tid & 15, ty = tid >> 4;
    float acc[8][4] = {};
    for (int k0 = 0; k0 < SI_; k0 += BKT) {
        #pragma unroll
        for (int l = 0; l < 2; l++) {
            int f = tid + l * 256, row = f >> 2, kq = (f & 3) << 2;
            float4 v = *(const float4*)(A + (size_t)(m0 + row) * SI_ + k0 + kq);
            As[kq][row] = v.x; As[kq+1][row] = v.y; As[kq+2][row] = v.z; As[kq+3][row] = v.w;
        }
        {
            int f = tid, row = f >> 2, kq = (f & 3) << 2;
            float4 v = *(const float4*)(B + (size_t)(n0 + row) * SI_ + k0 + kq);
            Bs[kq][row] = v.x; Bs[kq+1][row] = v.y; Bs[kq+2][row] = v.z; Bs[kq+3][row] = v.w;
        }
        __syncthreads();
        #pragma unroll
        for (int kk = 0; kk < BKT; kk++) {
            float4 a0 = *(const float4*)&As[kk][ty * 8];
            float4 a1 = *(const float4*)&As[kk][ty * 8 + 4];
            float4 b  = *(const float4*)&Bs[kk][tx * 4];
            float av[8] = {a0.x,a0.y,a0.z,a0.w,a1.x,a1.y,a1.z,a1.w};
            float bv[4] = {b.x,b.y,b.z,b.w};
            #pragma unroll
            for (int i = 0; i < 8; i++)
                #pragma unroll
                for (int j = 0; j < 4; j++)
                    acc[i][j] = fmaf(av[i], bv[j], acc[i][j]);
        }
        __syncthreads();
    }
    #pragma unroll
    for (int i = 0; i < 8; i++) {
        int t = m0 + ty * 8 + i;
        int s0 = tok_slot[2*t], s1 = tok_slot[2*t+1];
        float sg = sgate[t];
        float4 p0 = *(const float4*)(out_pair + (size_t)s0 * D_ + n0 + tx * 4);
        float4 p1 = *(const float4*)(out_pair + (size_t)s1 * D_ + n0 + tx * 4);
        float4 hv = *(const float4*)(h + (size_t)t * D_ + n0 + tx * 4);
        float4 o;
        o.x = hv.x + p0.x + p1.x + sg * acc[i][0];
        o.y = hv.y + p0.y + p1.y + sg * acc[i][1];
        o.z = hv.z + p0.z + p1.z + sg * acc[i][2];
        o.w = hv.w + p0.w + p1.w + sg * acc[i][3];
        *(float4*)(out + (size_t)t * D_ + n0 + tx * 4) = o;
    }
}

// ---------------- launch ----------------
extern "C" void kernel_launch(void* const* d_in, const int* in_sizes, int n_in,
                              void* d_out, int out_size, void* d_ws, size_t ws_size,
                              hipStream_t stream)
{
    const float* hidden = (const float*)d_in[0];
    const int* pos_ids  = (const int*)d_in[1];
    const float* q_w = (const float*)d_in[2];
    const float* q_b = (const float*)d_in[3];
    const float* k_w = (const float*)d_in[4];
    const float* k_b = (const float*)d_in[5];
    const float* v_w = (const float*)d_in[6];
    const float* v_b = (const float*)d_in[7];
    const float* o_w = (const float*)d_in[8];
    const float* ln1_w = (const float*)d_in[9];
    const float* ln2_w = (const float*)d_in[10];
    const float* router_w = (const float*)d_in[11];
    const float* eg = (const float*)d_in[12];
    const float* eu = (const float*)d_in[13];
    const float* ed = (const float*)d_in[14];
    const float* sgw = (const float*)d_in[15];
    const float* suw = (const float*)d_in[16];
    const float* sdw = (const float*)d_in[17];
    const float* segw = (const float*)d_in[18];
    float* out = (float*)d_out;

    char* ws = (char*)d_ws;
    const size_t MBy = 1024 * 1024;
    float* x      = (float*)(ws + 0 * MBy);     // [T,D]   (dead after v-proj)
    float* qb     = (float*)(ws + 8 * MBy);     // [T,2048]
    float* kb     = (float*)(ws + 16 * MBy);    // [T,512]
    float* vb     = (float*)(ws + 18 * MBy);    // [T,512]
    float* ob     = (float*)(ws + 20 * MBy);    // [T,D]
    float* hb     = (float*)(ws + 28 * MBy);    // [T,D]  residual2, live to end
    float* x2     = (float*)(ws + 36 * MBy);    // [T,D]
    float* scores = (float*)(ws + 44 * MBy);    // [16,1024,1024] = 67 MB
    float* act      = (float*)(ws + 0 * MBy);   // alias x/qb/kb (dead); [<=3064, I]
    float* out_pair = (float*)(ws + 44 * MBy);  // alias scores (dead); [<=3064, D]
    float* sh_g   = (float*)(ws + 76 * MBy);    // [T,SI] 23 MB
    float* sh_u   = (float*)(ws + 100 * MBy);   // [T,SI] 23 MB
    char* smallb  = ws + 124 * MBy;
    int*   topk_i = (int*)(smallb);
    float* topk_w = (float*)(smallb + 8 * 1024);
    int*   tok_slot = (int*)(smallb + 16 * 1024);
    float* sgate  = (float*)(smallb + 24 * 1024);
    int*   counts = (int*)(smallb + 28 * 1024);
    int*   cursor = (int*)(smallb + 28 * 1024 + 64);
    int*   offs   = (int*)(smallb + 28 * 1024 + 128);
    int*   pair_token = (int*)(smallb + 32 * 1024);
    float* pair_w = (float*)(smallb + 48 * 1024);

    hipMemsetAsync(smallb + 28 * 1024, 0, 192, stream);          // counts, cursor, offs
    hipMemsetAsync(pair_token, 0xFF, 4096 * sizeof(int), stream); // padding slots = -1

    dim3 blk(256);
    rmsnorm_k<<<T_, blk, 0, stream>>>(hidden, ln1_w, x);
    gemm_bt<<<dim3(D_/BN, T_/BM, 1), blk, 0, stream>>>(x, D_, 0, q_w, D_, 0, 1, qb, D_, 0, q_b, nullptr, 1.f, D_, 0);
    gemm_bt<<<dim3((KVH_*HD_)/BN, T_/BM, 1), blk, 0, stream>>>(x, D_, 0, k_w, D_, 0, 1, kb, KVH_*HD_, 0, k_b, nullptr, 1.f, D_, 0);
    gemm_bt<<<dim3((KVH_*HD_)/BN, T_/BM, 1), blk, 0, stream>>>(x, D_, 0, v_w, D_, 0, 1, vb, KVH_*HD_, 0, v_b, nullptr, 1.f, D_, 0);
    rope_k<<<T_, blk, 0, stream>>>(qb, kb, pos_ids);
    gemm_bt<<<dim3(T_/BN, T_/BM, NH_), blk, 0, stream>>>(
        qb, D_, 128, kb, KVH_*HD_, 128, 4, scores, T_, (long)T_*T_,
        nullptr, nullptr, 0.08838834764831845f, HD_, 1);
    softmax_k<<<dim3(T_, NH_), blk, 0, stream>>>(scores);
    gemm_bn_pv<<<dim3(HD_/BN, T_/BM, NH_), blk, 0, stream>>>(
        scores, T_, (long)T_*T_, vb, KVH_*HD_, 128, 4, ob, D_, 128);
    gemm_bt<<<dim3(D_/BN, T_/BM, 1), blk, 0, stream>>>(ob, D_, 0, o_w, D_, 0, 1, hb, D_, 0, nullptr, hidden, 1.f, D_, 0);
    rmsnorm_k<<<T_, blk, 0, stream>>>(hb, ln2_w, x2);
    router_k<<<T_, blk, 0, stream>>>(x2, router_w, segw, topk_i, topk_w, counts, sgate);
    offsets_k<<<1, 64, 0, stream>>>(counts, offs);
    scatter_k<<<4, blk, 0, stream>>>(topk_i, topk_w, offs, cursor, pair_token, pair_w, tok_slot);
    moe_phase1<<<dim3(I_/BN, T_/BM, E_), blk, 0, stream>>>(x2, eg, eu, pair_token, counts, offs, act);
    moe_phase2<<<dim3(D_/BN, T_/BM, E_), blk, 0, stream>>>(act, ed, pair_token, pair_w, counts, offs, out_pair);
    gemm_bt<<<dim3(SI_/BN, T_/BM, 1), blk, 0, stream>>>(x2, D_, 0, sgw, D_, 0, 1, sh_g, SI_, 0, nullptr, nullptr, 1.f, D_, 0);
    gemm_bt<<<dim3(SI_/BN, T_/BM, 1), blk, 0, stream>>>(x2, D_, 0, suw, D_, 0, 1, sh_u, SI_, 0, nullptr, nullptr, 1.f, D_, 0);
    silumul_k<<<(T_ * SI_ / 4) / 256, blk, 0, stream>>>(sh_g, sh_u);
    shared_down_final<<<dim3(D_/BN, T_/BM, 1), blk, 0, stream>>>(sh_g, sdw, hb, out_pair, tok_slot, sgate, out);
}

// Round 3
// 1290.380 us; speedup vs baseline: 2.6657x; 2.6657x over previous
//
#include <hip/hip_runtime.h>
#include <math.h>

#define T_   1024
#define D_   2048
#define HD_  128
#define NH_  16
#define KVH_ 4
#define E_   8
#define I_   1408
#define SI_  5632

typedef unsigned short u16;
typedef __bf16 bf16x8 __attribute__((ext_vector_type(8)));
typedef float f32x4 __attribute__((ext_vector_type(4)));

__device__ __forceinline__ u16 f2bf(float f) {
    union { float f; unsigned int u; } v; v.f = f;
    unsigned int r = v.u + 0x7fffu + ((v.u >> 16) & 1u);
    return (u16)(r >> 16);
}
__device__ __forceinline__ float bf2f(u16 h) {
    union { unsigned int u; float f; } v; v.u = ((unsigned int)h) << 16;
    return v.f;
}

__device__ __forceinline__ void ldsld16(const u16* g, u16* l) {
    __builtin_amdgcn_global_load_lds(
        (const __attribute__((address_space(1))) void*)g,
        (__attribute__((address_space(3))) void*)l, 16, 0, 0);
}

// ================= bf16 MFMA GEMM (m97 structure), optional hi/lo split =================
// C_tile[128x128] = A[M,K] @ B[N,K]^T. SPLIT=1: A,B have lo-planes at +psA/+psB (u16 elems),
// 3-MFMA per product (hi*hi + hi*lo + lo*hi) for ~f32 precision.
// mode: 0 f32 out (+bias)(+residual); 1 bf16 out; 2 *pair_w f32 out; 3 final combine;
//       4 split bf16 out (hi plane + lo plane at +psC)
template<int F32B, int SPLIT>
__global__ __launch_bounds__(256) void mm_k(
    const u16* __restrict__ A, long sAz, int lda, long psA,
    const void* __restrict__ B, long sBz, int bdiv, int ldb, long psB,
    void* __restrict__ C, long sCz, int ldc, long psC,
    int K, int pvkeff, int causal, int gatherA,
    const float* __restrict__ bias,
    const float* __restrict__ residual,
    int mode,
    const int* __restrict__ offs, const int* __restrict__ counts,
    const int* __restrict__ pair_token, const float* __restrict__ pair_w,
    const float* __restrict__ hbp, const int* __restrict__ tok_slot,
    const float* __restrict__ sgate, const float* __restrict__ out_pair)
{
    constexpr int PL = SPLIT ? 2 : 1;
    __shared__ u16 As[PL * 4096];
    __shared__ u16 Bs[PL * 4096];
    int m0 = blockIdx.y * 128, n0 = blockIdx.x * 128, z = blockIdx.z;
    if (causal && n0 >= m0 + 128) return;
    const u16* Ae = A;
    const void* Be = B;
    const int* rowtok = nullptr;
    long coff = 0;
    int base = 0;
    if (offs) {
        base = offs[z];
        int padded = (counts[z] + 127) & ~127;
        if (m0 >= padded) return;
        Be = (const void*)((const char*)B + (size_t)sBz * z * (F32B ? 4 : 2));
        if (gatherA) rowtok = pair_token + base;
        else Ae = A + (size_t)base * lda;
        coff = (long)base * ldc;
    } else {
        Ae = A + (size_t)sAz * z;
        Be = (const void*)((const char*)B + (size_t)sBz * (z / bdiv) * (F32B ? 4 : 2));
        coff = sCz * (long)z;
    }
    int keff = pvkeff ? (m0 + 128) : K;

    const int tid = threadIdx.x;
    const int r0 = tid >> 2, r1 = (tid + 256) >> 2;
    const int seg = tid & 3;
    int ar0 = m0 + r0, ar1 = m0 + r1;
    if (rowtok) {
        int t0 = rowtok[m0 + r0]; ar0 = t0 < 0 ? 0 : t0;
        int t1 = rowtok[m0 + r1]; ar1 = t1 < 0 ? 0 : t1;
    }
    const u16* ga0 = Ae + (size_t)ar0 * lda + seg * 8;
    const u16* ga1 = Ae + (size_t)ar1 * lda + seg * 8;
    u16* la0 = As + tid * 8;
    u16* la1 = As + (tid + 256) * 8;

    const u16* gb0h = nullptr; const u16* gb1h = nullptr;
    const float* gb0f = nullptr; const float* gb1f = nullptr;
    if constexpr (F32B) {
        const float* Bf = (const float*)Be;
        gb0f = Bf + (size_t)(n0 + r0) * ldb + seg * 8;
        gb1f = Bf + (size_t)(n0 + r1) * ldb + seg * 8;
    } else {
        const u16* Bh = (const u16*)Be;
        gb0h = Bh + (size_t)(n0 + r0) * ldb + seg * 8;
        gb1h = Bh + (size_t)(n0 + r1) * ldb + seg * 8;
    }
    u16* lb0 = Bs + tid * 8;
    u16* lb1 = Bs + (tid + 256) * 8;

    const int lane = tid & 63, wave = tid >> 6;
    const int wr = (wave >> 1) * 64, wc = (wave & 1) * 64;
    const int lr = lane & 15, quad = lane >> 4;
    const u16* Ard = As + (wr + lr) * 32 + quad * 8;
    const u16* Brd = Bs + (wc + lr) * 32 + quad * 8;

    f32x4 acc[4][4];
    #pragma unroll
    for (int i = 0; i < 4; i++)
        #pragma unroll
        for (int j = 0; j < 4; j++) { acc[i][j][0]=0.f; acc[i][j][1]=0.f; acc[i][j][2]=0.f; acc[i][j][3]=0.f; }

    for (int k0 = 0; k0 < keff; k0 += 32) {
        __syncthreads();
        ldsld16(ga0 + k0, la0);
        ldsld16(ga1 + k0, la1);
        if constexpr (SPLIT) {
            ldsld16(ga0 + psA + k0, la0 + 4096);
            ldsld16(ga1 + psA + k0, la1 + 4096);
        }
        if constexpr (F32B) {
            float4 x0 = *(const float4*)(gb0f + k0);
            float4 x1 = *(const float4*)(gb0f + k0 + 4);
            float4 y0 = *(const float4*)(gb1f + k0);
            float4 y1 = *(const float4*)(gb1f + k0 + 4);
            uint4 w0, w1;
            w0.x = (unsigned)f2bf(x0.x) | ((unsigned)f2bf(x0.y) << 16);
            w0.y = (unsigned)f2bf(x0.z) | ((unsigned)f2bf(x0.w) << 16);
            w0.z = (unsigned)f2bf(x1.x) | ((unsigned)f2bf(x1.y) << 16);
            w0.w = (unsigned)f2bf(x1.z) | ((unsigned)f2bf(x1.w) << 16);
            w1.x = (unsigned)f2bf(y0.x) | ((unsigned)f2bf(y0.y) << 16);
            w1.y = (unsigned)f2bf(y0.z) | ((unsigned)f2bf(y0.w) << 16);
            w1.z = (unsigned)f2bf(y1.x) | ((unsigned)f2bf(y1.y) << 16);
            w1.w = (unsigned)f2bf(y1.z) | ((unsigned)f2bf(y1.w) << 16);
            *(uint4*)lb0 = w0;
            *(uint4*)lb1 = w1;
        } else {
            ldsld16(gb0h + k0, lb0);
            ldsld16(gb1h + k0, lb1);
            if constexpr (SPLIT) {
                ldsld16(gb0h + psB + k0, lb0 + 4096);
                ldsld16(gb1h + psB + k0, lb1 + 4096);
            }
        }
        __syncthreads();
        bf16x8 ah[4], bh[4];
        #pragma unroll
        for (int i = 0; i < 4; i++) ah[i] = *(const bf16x8*)(Ard + i * 512);
        #pragma unroll
        for (int j = 0; j < 4; j++) bh[j] = *(const bf16x8*)(Brd + j * 512);
        if constexpr (SPLIT) {
            bf16x8 al[4], bl[4];
            #pragma unroll
            for (int i = 0; i < 4; i++) al[i] = *(const bf16x8*)(Ard + 4096 + i * 512);
            #pragma unroll
            for (int j = 0; j < 4; j++) bl[j] = *(const bf16x8*)(Brd + 4096 + j * 512);
            #pragma unroll
            for (int i = 0; i < 4; i++)
                #pragma unroll
                for (int j = 0; j < 4; j++) {
                    acc[i][j] = __builtin_amdgcn_mfma_f32_16x16x32_bf16(ah[i], bh[j], acc[i][j], 0, 0, 0);
                    acc[i][j] = __builtin_amdgcn_mfma_f32_16x16x32_bf16(al[i], bh[j], acc[i][j], 0, 0, 0);
                    acc[i][j] = __builtin_amdgcn_mfma_f32_16x16x32_bf16(ah[i], bl[j], acc[i][j], 0, 0, 0);
                }
        } else {
            #pragma unroll
            for (int i = 0; i < 4; i++)
                #pragma unroll
                for (int j = 0; j < 4; j++)
                    acc[i][j] = __builtin_amdgcn_mfma_f32_16x16x32_bf16(ah[i], bh[j], acc[i][j], 0, 0, 0);
        }
    }

    float* Cf = (float*)C;
    u16* Ch = (u16*)C;
    #pragma unroll
    for (int i = 0; i < 4; i++) {
        #pragma unroll
        for (int r = 0; r < 4; r++) {
            int m = m0 + wr + i * 16 + quad * 4 + r;
            if (mode == 2) {
                int tk = pair_token[base + m];
                if (tk < 0) continue;
                float pw = pair_w[base + m];
                #pragma unroll
                for (int j = 0; j < 4; j++) {
                    int n = n0 + wc + j * 16 + lr;
                    Cf[coff + (size_t)m * ldc + n] = acc[i][j][r] * pw;
                }
            } else if (mode == 3) {
                int s0 = tok_slot[2 * m], s1 = tok_slot[2 * m + 1];
                float sg = sgate[m];
                #pragma unroll
                for (int j = 0; j < 4; j++) {
                    int n = n0 + wc + j * 16 + lr;
                    float v = hbp[(size_t)m * ldc + n]
                            + out_pair[(size_t)s0 * ldc + n]
                            + out_pair[(size_t)s1 * ldc + n]
                            + sg * acc[i][j][r];
                    Cf[(size_t)m * ldc + n] = v;
                }
            } else if (mode == 4) {
                #pragma unroll
                for (int j = 0; j < 4; j++) {
                    int n = n0 + wc + j * 16 + lr;
                    float v = acc[i][j][r];
                    u16 hi = f2bf(v);
                    float lo = v - bf2f(hi);
                    Ch[coff + (size_t)m * ldc + n] = hi;
                    Ch[psC + coff + (size_t)m * ldc + n] = f2bf(lo);
                }
            } else {
                #pragma unroll
                for (int j = 0; j < 4; j++) {
                    int n = n0 + wc + j * 16 + lr;
                    float v = acc[i][j][r];
                    if (bias) v += bias[n];
                    if (residual) v += residual[(size_t)m * ldc + n];
                    if (mode == 0) Cf[coff + (size_t)m * ldc + n] = v;
                    else Ch[coff + (size_t)m * ldc + n] = f2bf(v);
                }
            }
        }
    }
}

// ================= small kernels =================
__global__ __launch_bounds__(256) void cvt_k(const float* __restrict__ s, u16* __restrict__ d, int n8) {
    int i = blockIdx.x * 256 + threadIdx.x;
    if (i >= n8) return;
    const float4* sp = (const float4*)s + (size_t)i * 2;
    float4 a = sp[0], b = sp[1];
    uint4 w;
    w.x = (unsigned)f2bf(a.x) | ((unsigned)f2bf(a.y) << 16);
    w.y = (unsigned)f2bf(a.z) | ((unsigned)f2bf(a.w) << 16);
    w.z = (unsigned)f2bf(b.x) | ((unsigned)f2bf(b.y) << 16);
    w.w = (unsigned)f2bf(b.z) | ((unsigned)f2bf(b.w) << 16);
    ((uint4*)d)[i] = w;
}

__device__ __forceinline__ void split2(float x, u16& h, u16& l) {
    h = f2bf(x);
    l = f2bf(x - bf2f(h));
}

__global__ __launch_bounds__(256) void cvt_split_k(const float* __restrict__ s,
                                                   u16* __restrict__ dh,
                                                   u16* __restrict__ dl, int n8) {
    int i = blockIdx.x * 256 + threadIdx.x;
    if (i >= n8) return;
    const float4* sp = (const float4*)s + (size_t)i * 2;
    float4 a = sp[0], b = sp[1];
    u16 h[8], l[8];
    split2(a.x, h[0], l[0]); split2(a.y, h[1], l[1]);
    split2(a.z, h[2], l[2]); split2(a.w, h[3], l[3]);
    split2(b.x, h[4], l[4]); split2(b.y, h[5], l[5]);
    split2(b.z, h[6], l[6]); split2(b.w, h[7], l[7]);
    uint4 wh, wl;
    wh.x = (unsigned)h[0] | ((unsigned)h[1] << 16); wh.y = (unsigned)h[2] | ((unsigned)h[3] << 16);
    wh.z = (unsigned)h[4] | ((unsigned)h[5] << 16); wh.w = (unsigned)h[6] | ((unsigned)h[7] << 16);
    wl.x = (unsigned)l[0] | ((unsigned)l[1] << 16); wl.y = (unsigned)l[2] | ((unsigned)l[3] << 16);
    wl.z = (unsigned)l[4] | ((unsigned)l[5] << 16); wl.w = (unsigned)l[6] | ((unsigned)l[7] << 16);
    ((uint4*)dh)[i] = wh;
    ((uint4*)dl)[i] = wl;
}

__global__ void biascat_k(const float* qb, const float* kb, const float* vb, float* o) {
    int i = blockIdx.x * 256 + threadIdx.x;
    if (i < 2048) o[i] = qb[i];
    else if (i < 2560) o[i] = kb[i - 2048];
    else if (i < 3072) o[i] = vb[i - 2560];
}

// RMSNorm: writes f32 (opt), plain bf16 (opt via yl==null) or split planes
__global__ __launch_bounds__(256) void rmsnorm_k(const float* __restrict__ x,
                                                 const float* __restrict__ w,
                                                 float* __restrict__ yf,
                                                 u16* __restrict__ yh,
                                                 u16* __restrict__ yl) {
    int t = blockIdx.x;
    int tid = threadIdx.x;
    const float4* row = (const float4*)(x + (size_t)t * D_);
    float4 v0 = row[tid];
    float4 v1 = row[tid + 256];
    float ss = v0.x*v0.x + v0.y*v0.y + v0.z*v0.z + v0.w*v0.w
             + v1.x*v1.x + v1.y*v1.y + v1.z*v1.z + v1.w*v1.w;
    __shared__ float red[4];
    int lane = tid & 63, wid = tid >> 6;
    #pragma unroll
    for (int o = 32; o > 0; o >>= 1) ss += __shfl_down(ss, o, 64);
    if (lane == 0) red[wid] = ss;
    __syncthreads();
    float s = red[0] + red[1] + red[2] + red[3];
    float inv = rsqrtf(s * (1.0f / D_) + 1e-6f);
    const float4* wv = (const float4*)w;
    float4 w0 = wv[tid], w1 = wv[tid + 256];
    float4 o0, o1;
    o0.x = v0.x * inv * w0.x; o0.y = v0.y * inv * w0.y;
    o0.z = v0.z * inv * w0.z; o0.w = v0.w * inv * w0.w;
    o1.x = v1.x * inv * w1.x; o1.y = v1.y * inv * w1.y;
    o1.z = v1.z * inv * w1.z; o1.w = v1.w * inv * w1.w;
    if (yf) {
        float4* outp = (float4*)(yf + (size_t)t * D_);
        outp[tid] = o0; outp[tid + 256] = o1;
    }
    if (yl) {
        u16 h[8], l[8];
        split2(o0.x, h[0], l[0]); split2(o0.y, h[1], l[1]);
        split2(o0.z, h[2], l[2]); split2(o0.w, h[3], l[3]);
        split2(o1.x, h[4], l[4]); split2(o1.y, h[5], l[5]);
        split2(o1.z, h[6], l[6]); split2(o1.w, h[7], l[7]);
        ushort4* oh = (ushort4*)(yh + (size_t)t * D_);
        ushort4* ol = (ushort4*)(yl + (size_t)t * D_);
        oh[tid] = make_ushort4(h[0], h[1], h[2], h[3]);
        oh[tid + 256] = make_ushort4(h[4], h[5], h[6], h[7]);
        ol[tid] = make_ushort4(l[0], l[1], l[2], l[3]);
        ol[tid + 256] = make_ushort4(l[4], l[5], l[6], l[7]);
    } else {
        ushort4* op = (ushort4*)(yh + (size_t)t * D_);
        op[tid] = make_ushort4(f2bf(o0.x), f2bf(o0.y), f2bf(o0.z), f2bf(o0.w));
        op[tid + 256] = make_ushort4(f2bf(o1.x), f2bf(o1.y), f2bf(o1.z), f2bf(o1.w));
    }
}

// RoPE: read qkv f32 [T,3072], write split q/k planes + split vT planes
__global__ __launch_bounds__(256) void rope_split_k(const float* __restrict__ qkv,
                                                    u16* __restrict__ qh,
                                                    u16* __restrict__ ql,
                                                    u16* __restrict__ vTh,
                                                    u16* __restrict__ vTl,
                                                    const int* __restrict__ pos) {
    int t = blockIdx.x;
    float fp = (float)pos[t];
    const float* row = qkv + (size_t)t * 3072;
    const double l2inv = 19.931568569324174 / 64.0;  // log2(1e6)/64
    for (int c = threadIdx.x; c < 3072; c += 256) {
        float val;
        if (c < 2560) {
            int d = c & 127, f = d & 63;
            float invf = (float)exp2(-(double)f * l2inv);
            float ang = fp * invf;                 // matches jax f32 outer product
            float sn, cs;
            sincosf(ang, &sn, &cs);
            float x1 = row[c];
            float xo = (d < 64) ? row[c + 64] : row[c - 64];
            val = (d < 64) ? (x1 * cs - xo * sn) : (x1 * cs + xo * sn);
        } else {
            val = row[c];
        }
        u16 h, l;
        split2(val, h, l);
        qh[(size_t)t * 3072 + c] = h;
        ql[(size_t)t * 3072 + c] = l;
        if (c >= 2560) {
            vTh[(size_t)(c - 2560) * 1024 + t] = h;
            vTl[(size_t)(c - 2560) * 1024 + t] = l;
        }
    }
}

// causal softmax with scale; reads f32 row, writes split bf16 P (hi plane | lo plane) in place
__global__ __launch_bounds__(256) void softmax_k(float* __restrict__ scores) {
    int qi = blockIdx.x, h = blockIdx.y;
    float* row = scores + ((size_t)h * T_ + qi) * T_;
    u16* orow = (u16*)row;
    int len = qi + 1;
    __shared__ float buf[1024];
    __shared__ float red[4];
    const float scale = 0.08838834764831845f;
    int tid = threadIdx.x, lane = tid & 63, wid = tid >> 6;
    float m = -3.0e38f;
    for (int i = tid; i < len; i += 256) {
        float v = row[i] * scale;
        buf[i] = v;
        m = fmaxf(m, v);
    }
    #pragma unroll
    for (int o = 32; o > 0; o >>= 1) m = fmaxf(m, __shfl_down(m, o, 64));
    if (lane == 0) red[wid] = m;
    __syncthreads();
    m = fmaxf(fmaxf(red[0], red[1]), fmaxf(red[2], red[3]));
    __syncthreads();
    float s = 0.f;
    for (int i = tid; i < len; i += 256) {
        float e = expf(buf[i] - m);
        buf[i] = e;
        s += e;
    }
    #pragma unroll
    for (int o = 32; o > 0; o >>= 1) s += __shfl_down(s, o, 64);
    if (lane == 0) red[wid] = s;
    __syncthreads();
    s = red[0] + red[1] + red[2] + red[3];
    float inv = 1.0f / s;
    __syncthreads();
    for (int i = tid; i < T_; i += 256) {
        float v = (i < len) ? buf[i] * inv : 0.f;
        u16 hi, lo;
        split2(v, hi, lo);
        orow[i] = hi;
        orow[1024 + i] = lo;
    }
}

__global__ __launch_bounds__(256) void router_k(
    const float* __restrict__ x2, const float* __restrict__ rw,
    const float* __restrict__ seg,
    int* __restrict__ topk_i, float* __restrict__ topk_w,
    int* __restrict__ counts, float* __restrict__ sgate)
{
    int t = blockIdx.x;
    const float4* xr = (const float4*)(x2 + (size_t)t * D_);
    float part[9];
    #pragma unroll
    for (int e = 0; e < 9; e++) part[e] = 0.f;
    for (int i = threadIdx.x; i < D_ / 4; i += 256) {
        float4 xv = xr[i];
        #pragma unroll
        for (int e = 0; e < 8; e++) {
            float4 wv = ((const float4*)(rw + (size_t)e * D_))[i];
            part[e] += xv.x*wv.x + xv.y*wv.y + xv.z*wv.z + xv.w*wv.w;
        }
        float4 gv = ((const float4*)seg)[i];
        part[8] += xv.x*gv.x + xv.y*gv.y + xv.z*gv.z + xv.w*gv.w;
    }
    __shared__ float red[9][4];
    int lane = threadIdx.x & 63, wid = threadIdx.x >> 6;
    #pragma unroll
    for (int e = 0; e < 9; e++) {
        float v = part[e];
        #pragma unroll
        for (int o = 32; o > 0; o >>= 1) v += __shfl_down(v, o, 64);
        if (lane == 0) red[e][wid] = v;
    }
    __syncthreads();
    if (threadIdx.x == 0) {
        float lg[9];
        #pragma unroll
        for (int e = 0; e < 9; e++) lg[e] = red[e][0] + red[e][1] + red[e][2] + red[e][3];
        float mx = lg[0];
        for (int e = 1; e < 8; e++) mx = fmaxf(mx, lg[e]);
        float p[8], s = 0.f;
        for (int e = 0; e < 8; e++) { p[e] = expf(lg[e] - mx); s += p[e]; }
        float invs = 1.0f / s;
        for (int e = 0; e < 8; e++) p[e] *= invs;
        int i0 = 0;
        for (int e = 1; e < 8; e++) if (p[e] > p[i0]) i0 = e;
        int i1 = (i0 == 0) ? 1 : 0;
        for (int e = 0; e < 8; e++) if (e != i0 && p[e] > p[i1]) i1 = e;
        topk_i[2*t] = i0; topk_i[2*t+1] = i1;
        topk_w[2*t] = p[i0]; topk_w[2*t+1] = p[i1];
        atomicAdd(&counts[i0], 1);
        atomicAdd(&counts[i1], 1);
        sgate[t] = 1.0f / (1.0f + expf(-lg[8]));
    }
}

__global__ void offsets_k(const int* __restrict__ counts, int* __restrict__ offs) {
    if (threadIdx.x == 0 && blockIdx.x == 0) {
        int o = 0;
        for (int e = 0; e < E_; e++) {
            offs[e] = o;
            o += (counts[e] + 127) & ~127;
        }
    }
}

__global__ __launch_bounds__(256) void scatter_k(
    const int* __restrict__ topk_i, const float* __restrict__ topk_w,
    const int* __restrict__ offs, int* __restrict__ cursor,
    int* __restrict__ pair_token, float* __restrict__ pair_w,
    int* __restrict__ tok_slot)
{
    int t = blockIdx.x * 256 + threadIdx.x;
    if (t >= T_) return;
    #pragma unroll
    for (int j = 0; j < 2; j++) {
        int e = topk_i[2*t+j];
        int pos = atomicAdd(&cursor[e], 1);
        int slot = offs[e] + pos;
        pair_token[slot] = t;
        pair_w[slot] = topk_w[2*t+j];
        tok_slot[2*t+j] = slot;
    }
}

__global__ __launch_bounds__(256) void silu_k(const float* __restrict__ gu,
                                              u16* __restrict__ act,
                                              int cols, int stride) {
    int r = blockIdx.y;
    int c = (blockIdx.x * 256 + threadIdx.x) * 4;
    if (c >= cols) return;
    const float* p = gu + (size_t)r * stride;
    float4 g = *(const float4*)(p + c);
    float4 u = *(const float4*)(p + cols + c);
    float4 o;
    o.x = g.x / (1.f + expf(-g.x)) * u.x;
    o.y = g.y / (1.f + expf(-g.y)) * u.y;
    o.z = g.z / (1.f + expf(-g.z)) * u.z;
    o.w = g.w / (1.f + expf(-g.w)) * u.w;
    *(ushort4*)(act + (size_t)r * cols + c) =
        make_ushort4(f2bf(o.x), f2bf(o.y), f2bf(o.z), f2bf(o.w));
}

// ================= launch =================
extern "C" void kernel_launch(void* const* d_in, const int* in_sizes, int n_in,
                              void* d_out, int out_size, void* d_ws, size_t ws_size,
                              hipStream_t stream)
{
    const float* hidden = (const float*)d_in[0];
    const int* pos_ids  = (const int*)d_in[1];
    const float* q_w = (const float*)d_in[2];
    const float* q_b = (const float*)d_in[3];
    const float* k_w = (const float*)d_in[4];
    const float* k_b = (const float*)d_in[5];
    const float* v_w = (const float*)d_in[6];
    const float* v_b = (const float*)d_in[7];
    const float* o_w = (const float*)d_in[8];
    const float* ln1_w = (const float*)d_in[9];
    const float* ln2_w = (const float*)d_in[10];
    const float* router_w = (const float*)d_in[11];
    const float* eg = (const float*)d_in[12];
    const float* eu = (const float*)d_in[13];
    const float* ed = (const float*)d_in[14];
    const float* sgw = (const float*)d_in[15];
    const float* suw = (const float*)d_in[16];
    const float* sdw = (const float*)d_in[17];
    const float* segw = (const float*)d_in[18];
    float* out = (float*)d_out;

    char* ws = (char*)d_ws;
    // --- phase-A arena (dead after attention), overlaid by phase-B buffers ---
    float* scores  = (float*)(ws + 0);            // 64 MB; P split planes in-place
    float* qb      = (float*)(ws + 67108864);     // 12 MB f32 qkv
    u16*   qkv_hi  = (u16*)(ws + 79691776);       // 6 MB
    u16*   qkv_lo  = (u16*)(ws + 85983232);       // 6 MB  (psA = 3145728 u16)
    u16*   vT_hi   = (u16*)(ws + 92274688);       // 1 MB
    u16*   vT_lo   = (u16*)(ws + 93323264);       // 1 MB  (ps = 524288)
    u16*   x_hi    = (u16*)(ws + 94371840);       // 4 MB
    u16*   x_lo    = (u16*)(ws + 98566144);       // 4 MB  (ps = 2097152)
    u16*   ob_hi   = (u16*)(ws + 102760448);      // 4 MB
    u16*   ob_lo   = (u16*)(ws + 106954752);      // 4 MB  (ps = 2097152)
    // --- persistent ---
    float* hb      = (float*)(ws + 111149056);    // 8 MB residual2
    float* x2      = (float*)(ws + 119537664);    // 8 MB
    u16*   x2_bf   = (u16*)(ws + 127926272);      // 4 MB
    float* out_pair= (float*)(ws + 132120576);    // 24 MB [3072,2048]
    // --- attention weights (overlaid by wsh/sdb after o_proj) ---
    u16*   wqkv_hi = (u16*)(ws + 157286400);      // 12 MB  (psB = 6291456)
    u16*   wqkv_lo = (u16*)(ws + 169869312);      // 12 MB
    u16*   owb_hi  = (u16*)(ws + 182452224);      // 8 MB   (psB = 4194304)
    u16*   owb_lo  = (u16*)(ws + 190840832);      // 8 MB
    u16*   wsh     = (u16*)(ws + 157286400);      // 44 MB overlay [11264,2048]
    u16*   sdb     = (u16*)(ws + 203423744);      // 22 MB overlay [2048,5632]
    // --- phase-B overlay of scores arena ---
    float* gu      = (float*)(ws + 0);            // 33.75 MB [3072,2816]
    u16*   act_bf  = (u16*)(ws + 34603008);       // 8.25 MB [3072,1408]
    float* shgu    = (float*)(ws + 0);            // 44 MB [1024,11264]
    u16*   actsh   = (u16*)(ws + 46137344);       // 11 MB [1024,5632]
    // --- small ---
    char*  smallb  = ws + 226492416;
    int*   topk_i   = (int*)(smallb);
    float* topk_w   = (float*)(smallb + 16384);
    int*   tok_slot = (int*)(smallb + 32768);
    float* sgate    = (float*)(smallb + 49152);
    int*   counts   = (int*)(smallb + 53248);
    int*   cursor   = (int*)(smallb + 53312);
    int*   offs     = (int*)(smallb + 53376);
    int*   pair_token = (int*)(smallb + 57344);
    float* pair_w   = (float*)(smallb + 73728);
    float* qkvb     = (float*)(smallb + 90112);

    hipMemsetAsync(smallb + 53248, 0, 192, stream);
    hipMemsetAsync(pair_token, 0xFF, 4096 * sizeof(int), stream);

    dim3 blk(256);
    const void* np = nullptr;

    // attention weight split-conversions
    cvt_split_k<<<2048, blk, 0, stream>>>(q_w, wqkv_hi, wqkv_lo, 524288);
    cvt_split_k<<<512, blk, 0, stream>>>(k_w, wqkv_hi + 2048*2048, wqkv_lo + 2048*2048, 131072);
    cvt_split_k<<<512, blk, 0, stream>>>(v_w, wqkv_hi + 2560*2048, wqkv_lo + 2560*2048, 131072);
    biascat_k<<<12, blk, 0, stream>>>(q_b, k_b, v_b, qkvb);
    cvt_split_k<<<2048, blk, 0, stream>>>(o_w, owb_hi, owb_lo, 524288);

    // ---- attention (split-bf16, ~f32 precision) ----
    rmsnorm_k<<<T_, blk, 0, stream>>>(hidden, ln1_w, nullptr, x_hi, x_lo);
    mm_k<0,1><<<dim3(24, 8, 1), blk, 0, stream>>>(
        x_hi, 0, 2048, 2097152, wqkv_hi, 0, 1, 2048, 6291456,
        qb, 0, 3072, 0, 2048, 0, 0, 0, qkvb, nullptr, 0,
        nullptr, nullptr, nullptr, nullptr, nullptr, nullptr, nullptr, nullptr);
    rope_split_k<<<T_, blk, 0, stream>>>(qb, qkv_hi, qkv_lo, vT_hi, vT_lo, pos_ids);
    mm_k<0,1><<<dim3(8, 8, 16), blk, 0, stream>>>(
        qkv_hi, 128, 3072, 3145728, qkv_hi + 2048, 128, 4, 3072, 3145728,
        scores, 1048576, 1024, 0, 128, 0, 1, 0, nullptr, nullptr, 0,
        nullptr, nullptr, nullptr, nullptr, nullptr, nullptr, nullptr, nullptr);
    softmax_k<<<dim3(T_, NH_), blk, 0, stream>>>(scores);
    mm_k<0,1><<<dim3(1, 8, 16), blk, 0, stream>>>(
        (u16*)scores, 2097152, 2048, 1024, vT_hi, 131072, 4, 1024, 524288,
        ob_hi, 128, 2048, 2097152, 1024, 1, 0, 0, nullptr, nullptr, 4,
        nullptr, nullptr, nullptr, nullptr, nullptr, nullptr, nullptr, nullptr);
    mm_k<0,1><<<dim3(16, 8, 1), blk, 0, stream>>>(
        ob_hi, 0, 2048, 2097152, owb_hi, 0, 1, 2048, 4194304,
        hb, 0, 2048, 0, 2048, 0, 0, 0, nullptr, hidden, 0,
        nullptr, nullptr, nullptr, nullptr, nullptr, nullptr, nullptr, nullptr);

    // shared-expert weight conversions (overlay attention weights — after o_proj in stream order)
    cvt_k<<<5632, blk, 0, stream>>>(sgw, wsh, 1441792);
    cvt_k<<<5632, blk, 0, stream>>>(suw, wsh + 5632*2048, 1441792);
    cvt_k<<<5632, blk, 0, stream>>>(sdw, sdb, 1441792);

    // ---- router + sparse MoE (plain bf16 — smooth error only) ----
    rmsnorm_k<<<T_, blk, 0, stream>>>(hb, ln2_w, x2, x2_bf, nullptr);
    router_k<<<T_, blk, 0, stream>>>(x2, router_w, segw, topk_i, topk_w, counts, sgate);
    offsets_k<<<1, 64, 0, stream>>>(counts, offs);
    scatter_k<<<4, blk, 0, stream>>>(topk_i, topk_w, offs, cursor, pair_token, pair_w, tok_slot);
    mm_k<1,0><<<dim3(11, 8, 8), blk, 0, stream>>>(
        x2_bf, 0, 2048, 0, eg, (long)I_ * D_, 1, 2048, 0,
        gu, 0, 2816, 0, 2048, 0, 0, 1, nullptr, nullptr, 0,
        offs, counts, pair_token, pair_w, nullptr, nullptr, nullptr, nullptr);
    mm_k<1,0><<<dim3(11, 8, 8), blk, 0, stream>>>(
        x2_bf, 0, 2048, 0, eu, (long)I_ * D_, 1, 2048, 0,
        gu + 1408, 0, 2816, 0, 2048, 0, 0, 1, nullptr, nullptr, 0,
        offs, counts, pair_token, pair_w, nullptr, nullptr, nullptr, nullptr);
    silu_k<<<dim3(2, 3072), blk, 0, stream>>>(gu, act_bf, 1408, 2816);
    mm_k<1,0><<<dim3(16, 8, 8), blk, 0, stream>>>(
        act_bf, 0, 1408, 0, ed, (long)D_ * I_, 1, 1408, 0,
        out_pair, 0, 2048, 0, 1408, 0, 0, 0, nullptr, nullptr, 2,
        offs, counts, pair_token, pair_w, nullptr, nullptr, nullptr, nullptr);

    // ---- shared expert + final combine ----
    mm_k<0,0><<<dim3(88, 8, 1), blk, 0, stream>>>(
        x2_bf, 0, 2048, 0, wsh, 0, 1, 2048, 0,
        shgu, 0, 11264, 0, 2048, 0, 0, 0, nullptr, nullptr, 0,
        nullptr, nullptr, nullptr, nullptr, nullptr, nullptr, nullptr, nullptr);
    silu_k<<<dim3(6, 1024), blk, 0, stream>>>(shgu, actsh, 5632, 11264);
    mm_k<0,0><<<dim3(16, 8, 1), blk, 0, stream>>>(
        actsh, 0, 5632, 0, sdb, 0, 1, 5632, 0,
        out, 0, 2048, 0, 5632, 0, 0, 0, nullptr, nullptr, 3,
        nullptr, nullptr, nullptr, nullptr, hb, tok_slot, sgate, out_pair);
    (void)np;
}